// Round 5
// baseline (657.225 us; speedup 1.0000x reference)
//
#include <hip/hip_runtime.h>
#include <hip/hip_bf16.h>
#include <stdint.h>

typedef __attribute__((ext_vector_type(4))) float f32x4;
typedef __attribute__((ext_vector_type(8))) short bf16x8;

// ---- workspace layout (bytes) ----
#define OFF_X1B   0UL
#define OFF_X2B   4194304UL
#define OFF_PEB   8388608UL
#define OFF_WQT   12582912UL
#define OFF_WKT   13107200UL
#define OFF_WVT   13631488UL
#define OFF_WPT   14155776UL
#define OFF_WO1T  14680064UL
#define OFF_WO2T  15204352UL
#define OFF_QU1   15728640UL
#define OFF_QV1   19922944UL
#define OFF_K1    24117248UL
#define OFF_V1    28311552UL
#define OFF_QU2   32505856UL
#define OFF_QV2   36700160UL
#define OFF_K2    40894464UL
#define OFF_V2    45088768UL
#define OFF_POSP  49283072UL
#define OFF_VT1   53477376UL
#define OFF_VT2   57671680UL
#define OFF_CP1   61865984UL
#define OFF_CP2   66060288UL

// ---- d_out offsets (f32 elements) ----
#define CTX1_OFF  0UL
#define ATTN1_OFF 2097152UL
#define CTX2_OFF  35651584UL
#define ATTN2_OFF 37748736UL

struct PP {
  const float* x1; const float* x2; const float* pe; const unsigned char* mask;
  const float* Wq; const float* bq; const float* Wk; const float* bk;
  const float* Wv; const float* bv; const float* Wp;
  const float* ub; const float* vb;
  const float* Wo1; const float* bo1; const float* Wo2; const float* bo2;
  float* out; char* ws;
};

__device__ __forceinline__ short f2bf(float f){
  union { float f; unsigned u; } v; v.f = f;
  unsigned r = v.u + 0x7FFFu + ((v.u >> 16) & 1u);
  return (short)(r >> 16);
}
__device__ __forceinline__ float bf2f(short s){
  union { unsigned u; float f; } v; v.u = ((unsigned)(unsigned short)s) << 16;
  return v.f;
}

// ---- f32 -> bf16 convert for x1, x2, pos_embedding ----
__global__ __launch_bounds__(256) void k_cvt(PP p){
  int z = blockIdx.y;
  const float* s = (z==0) ? p.x1 : (z==1) ? p.x2 : p.pe;
  short* d = (short*)(p.ws + (z==0 ? OFF_X1B : z==1 ? OFF_X2B : OFF_PEB));
  size_t i = ((size_t)(blockIdx.x*256 + threadIdx.x))*8;
  float4 a = *(const float4*)(s+i);
  float4 b = *(const float4*)(s+i+4);
  bf16x8 o;
  o[0]=f2bf(a.x); o[1]=f2bf(a.y); o[2]=f2bf(a.z); o[3]=f2bf(a.w);
  o[4]=f2bf(b.x); o[5]=f2bf(b.y); o[6]=f2bf(b.z); o[7]=f2bf(b.w);
  *(bf16x8*)(d+i) = o;
}

// ---- weight transpose + convert: WT[n][k] = bf16(W[k][n]) ----
__global__ __launch_bounds__(256) void k_cvtw(PP p){
  int z = blockIdx.y;
  const float* src = (z==0)?p.Wq:(z==1)?p.Wk:(z==2)?p.Wv:(z==3)?p.Wp:(z==4)?p.Wo1:p.Wo2;
  short* dst = (short*)(p.ws + ((z==0)?OFF_WQT:(z==1)?OFF_WKT:(z==2)?OFF_WVT:(z==3)?OFF_WPT:(z==4)?OFF_WO1T:OFF_WO2T));
  int tile = blockIdx.x;             // 8x8 tiles of 64x64
  int k0 = (tile & 7)*64, n0 = (tile >> 3)*64;
  __shared__ short tl[64][68];
  int t = threadIdx.x;
  int i = t>>2, jc = (t&3)*16;
  const float* s = src + (size_t)(k0+i)*512 + n0 + jc;
  #pragma unroll
  for (int q=0;q<16;q+=4){
    float4 v = *(const float4*)(s+q);
    tl[i][jc+q+0]=f2bf(v.x); tl[i][jc+q+1]=f2bf(v.y);
    tl[i][jc+q+2]=f2bf(v.z); tl[i][jc+q+3]=f2bf(v.w);
  }
  __syncthreads();
  int n = t>>2, kp2 = (t&3)*16;
  bf16x8 o0, o1;
  #pragma unroll
  for (int q=0;q<8;q++){ o0[q] = tl[kp2+q][n]; o1[q] = tl[kp2+8+q][n]; }
  short* dp = dst + (size_t)(n0+n)*512 + k0 + kp2;
  *(bf16x8*)dp = o0;
  *(bf16x8*)(dp+8) = o1;
}

// ---- generic 128x128 MFMA GEMM over job table ----
// jobs 0-6: projections (bf16 out, optional dual out + head-bias), 7-8: output proj (f32 out)
__global__ __launch_bounds__(256) void k_gemm(PP p, int job_base){
  const int job = job_base + blockIdx.z;
  char* ws = p.ws;
  const short *A, *BT; const float* bias = nullptr;
  short* o0 = nullptr; const float* eb0 = nullptr;
  short* o1 = nullptr; const float* eb1 = nullptr;
  float* of = nullptr;
  switch(job){
    case 0: A=(const short*)(ws+OFF_X1B); BT=(const short*)(ws+OFF_WQT); bias=p.bq;
            o0=(short*)(ws+OFF_QU1); eb0=p.ub; o1=(short*)(ws+OFF_QV1); eb1=p.vb; break;
    case 1: A=(const short*)(ws+OFF_X1B); BT=(const short*)(ws+OFF_WKT); bias=p.bk; o0=(short*)(ws+OFF_K1); break;
    case 2: A=(const short*)(ws+OFF_X1B); BT=(const short*)(ws+OFF_WVT); bias=p.bv; o0=(short*)(ws+OFF_V1); break;
    case 3: A=(const short*)(ws+OFF_X2B); BT=(const short*)(ws+OFF_WQT); bias=p.bq;
            o0=(short*)(ws+OFF_QU2); eb0=p.ub; o1=(short*)(ws+OFF_QV2); eb1=p.vb; break;
    case 4: A=(const short*)(ws+OFF_X2B); BT=(const short*)(ws+OFF_WKT); bias=p.bk; o0=(short*)(ws+OFF_K2); break;
    case 5: A=(const short*)(ws+OFF_X2B); BT=(const short*)(ws+OFF_WVT); bias=p.bv; o0=(short*)(ws+OFF_V2); break;
    case 6: A=(const short*)(ws+OFF_PEB); BT=(const short*)(ws+OFF_WPT); o0=(short*)(ws+OFF_POSP); break;
    case 7: A=(const short*)(ws+OFF_CP1); BT=(const short*)(ws+OFF_WO1T); bias=p.bo1; of=p.out + CTX1_OFF; break;
    default: A=(const short*)(ws+OFF_CP2); BT=(const short*)(ws+OFF_WO2T); bias=p.bo2; of=p.out + CTX2_OFF; break;
  }
  __shared__ short As[128][72];
  __shared__ short Bs[128][72];
  const int t = threadIdx.x, w = t>>6, l = t&63, g = l>>4, r = l&15;
  const int m0 = blockIdx.x*128, n0 = blockIdx.y*128;
  const int wm = (w>>1)*64, wn = (w&1)*64;
  f32x4 acc[4][4];
  #pragma unroll
  for (int i=0;i<4;i++)
    #pragma unroll
    for(int j=0;j<4;j++) acc[i][j] = (f32x4){0.f,0.f,0.f,0.f};

  for (int k0=0; k0<512; k0+=64){
    __syncthreads();
    #pragma unroll
    for (int i=0;i<4;i++){
      int c = t + 256*i;
      int row = c>>3, kc = (c&7)*8;
      *(bf16x8*)&As[row][kc] = *(const bf16x8*)(A + (size_t)(m0+row)*512 + k0 + kc);
      *(bf16x8*)&Bs[row][kc] = *(const bf16x8*)(BT + (size_t)(n0+row)*512 + k0 + kc);
    }
    __syncthreads();
    #pragma unroll
    for (int kk=0; kk<64; kk+=32){
      bf16x8 a[4], bb[4];
      #pragma unroll
      for (int i=0;i<4;i++) a[i] = *(const bf16x8*)&As[wm+16*i+r][kk+8*g];
      #pragma unroll
      for (int j=0;j<4;j++) bb[j] = *(const bf16x8*)&Bs[wn+16*j+r][kk+8*g];
      #pragma unroll
      for (int i=0;i<4;i++)
        #pragma unroll
        for (int j=0;j<4;j++)
          acc[i][j] = __builtin_amdgcn_mfma_f32_16x16x32_bf16(a[i], bb[j], acc[i][j], 0,0,0);
    }
  }
  #pragma unroll
  for (int i=0;i<4;i++){
    #pragma unroll
    for (int j=0;j<4;j++){
      int col = n0 + wn + 16*j + r;
      float bv = bias ? bias[col] : 0.f;
      float e0 = eb0 ? eb0[col] : 0.f;
      float e1 = eb1 ? eb1[col] : 0.f;
      #pragma unroll
      for (int rr=0; rr<4; rr++){
        size_t row = (size_t)(m0 + wm + 16*i + 4*g + rr);
        float val = acc[i][j][rr] + bv;
        if (of) of[row*512 + col] = val;
        else {
          o0[row*512 + col] = f2bf(val + e0);
          if (o1) o1[row*512 + col] = f2bf(val + e1);
        }
      }
    }
  }
}

// ---- v -> vT[b][h][d][s] transpose (bf16) ----
__global__ __launch_bounds__(256) void k_vtrans(PP p){
  int stile = blockIdx.x, bh = blockIdx.y, st = blockIdx.z;
  const short* v = (const short*)(p.ws + (st? OFF_V2:OFF_V1));
  short* vT = (short*)(p.ws + (st? OFF_VT2:OFF_VT1));
  int b = bh>>3, h = bh&7;
  __shared__ short tl[64][68];
  int t = threadIdx.x;
  int i = t>>2, jc = (t&3)*16;
  const short* src = v + ((size_t)(b*1024 + stile*64 + i))*512 + h*64 + jc;
  *(bf16x8*)&tl[i][jc]   = *(const bf16x8*)src;
  *(bf16x8*)&tl[i][jc+8] = *(const bf16x8*)(src+8);
  __syncthreads();
  int d = t>>2, sp = (t&3)*16;
  bf16x8 o0, o1;
  #pragma unroll
  for (int q=0;q<8;q++){ o0[q]=tl[sp+q][d]; o1[q]=tl[sp+8+q][d]; }
  short* dp = vT + ((size_t)(bh*64 + d))*1024 + stile*64 + sp;
  *(bf16x8*)dp = o0;
  *(bf16x8*)(dp+8) = o1;
}

// ---- fused rel-attention: one block = (stream, b, h, 16 q-rows) ----
__global__ __launch_bounds__(256) void k_attn(PP p){
  const int t = threadIdx.x, w = t>>6, l = t&63, g = l>>4, r = l&15;
  const int qt = blockIdx.x, bh = blockIdx.y, st = blockIdx.z;
  const int b = bh>>3, h = bh&7;
  const int r0 = qt*16;
  char* ws = p.ws;
  const short* qu = (const short*)(ws + (st? OFF_QU2:OFF_QU1));
  const short* qv = (const short*)(ws + (st? OFF_QV2:OFF_QV1));
  const short* kp = (const short*)(ws + (st? OFF_K2:OFF_K1));
  const short* vT = (const short*)(ws + (st? OFF_VT2:OFF_VT1));
  short* cp = (short*)(ws + (st? OFF_CP2:OFF_CP1));
  float* attn_out = p.out + (st? ATTN2_OFF : ATTN1_OFF);
  const short* posp = (const short*)(ws + OFF_POSP);

  union ScBuf { short ps[17][1024]; float sc[16][1024]; };
  __shared__ ScBuf u;   // 65536 B, overlaid phases

  // --- q fragments (content uses q+u, pos uses q+v; +1-row frag for rel-shift) ---
  bf16x8 aqu[2], aqv[2], aqv2[2];
  {
    size_t base = ((size_t)(b*1024 + r0 + r))*512 + h*64 + 8*g;
    int row2 = r0 + 16 + r; if (row2 > 1023) row2 = 1023;
    size_t base2 = ((size_t)(b*1024 + row2))*512 + h*64 + 8*g;
    #pragma unroll
    for (int ks=0; ks<2; ks++){
      aqu[ks]  = *(const bf16x8*)(qu + base  + ks*32);
      aqv[ks]  = *(const bf16x8*)(qv + base  + ks*32);
      aqv2[ks] = *(const bf16x8*)(qv + base2 + ks*32);
    }
  }

  // --- Phase B: pos_score panel rows r0..r0+16, all 1024 cols -> LDS bf16 ---
  {
    size_t pbase = ((size_t)(b*1024))*512 + h*64 + 8*g;
    #pragma unroll 4
    for (int tt=0; tt<16; tt++){
      int n = 256*w + 16*tt;
      f32x4 a0 = {0.f,0.f,0.f,0.f}, a1 = {0.f,0.f,0.f,0.f};
      #pragma unroll
      for (int ks=0; ks<2; ks++){
        bf16x8 bf = *(const bf16x8*)(posp + pbase + (size_t)(n + r)*512 + ks*32);
        a0 = __builtin_amdgcn_mfma_f32_16x16x32_bf16(aqv[ks],  bf, a0, 0,0,0);
        a1 = __builtin_amdgcn_mfma_f32_16x16x32_bf16(aqv2[ks], bf, a1, 0,0,0);
      }
      #pragma unroll
      for (int rr=0; rr<4; rr++) u.ps[4*g+rr][n+r] = f2bf(a0[rr]);
      if (g==0) u.ps[16][n+r] = f2bf(a1[0]);   // row r0+16, only D-row 0 of M-tile 1
    }
  }
  __syncthreads();

  // --- Phase C: content MFMA + rel-shifted ps + mask -> score regs ---
  f32x4 sca[16];
  {
    size_t kbase = ((size_t)(b*1024))*512 + h*64 + 8*g;
    const unsigned char* mk = p.mask + b*1024;
    #pragma unroll 4
    for (int tt=0; tt<16; tt++){
      int n = 256*w + 16*tt;
      f32x4 a0 = {0.f,0.f,0.f,0.f};
      #pragma unroll
      for (int ks=0; ks<2; ks++){
        bf16x8 bf = *(const bf16x8*)(kp + kbase + (size_t)(n + r)*512 + ks*32);
        a0 = __builtin_amdgcn_mfma_f32_16x16x32_bf16(aqu[ks], bf, a0, 0,0,0);
      }
      int s2 = n + r;
      bool msk = (mk[s2] != 0);
      #pragma unroll
      for (int rr=0; rr<4; rr++){
        int lr = 4*g + rr;
        int s1 = r0 + lr;
        float pv;
        if (s2 <= s1)        pv = bf2f(u.ps[lr][s2 + 1023 - s1]);
        else if (s2 == s1+1) pv = 0.f;
        else                 pv = bf2f(u.ps[lr+1][s2 - s1 - 2]);
        float sv = (a0[rr] + pv) * 0.04419417382415922f;  // 1/sqrt(512)
        if (msk) sv = -1e9f;
        sca[tt][rr] = sv;
      }
    }
  }
  __syncthreads();   // all ps reads complete before overlay write

  // --- write scores into f32 overlay (XOR-swizzled rows) ---
  #pragma unroll
  for (int tt=0; tt<16; tt++){
    int s2 = 256*w + 16*tt + r;
    #pragma unroll
    for (int rr=0; rr<4; rr++){
      int row = 4*g + rr;
      u.sc[row][s2 ^ ((row&7)<<3)] = sca[tt][rr];
    }
  }
  __syncthreads();

  // --- Phase D: softmax (wave w owns rows 4w..4w+3), write attn to HBM ---
  #pragma unroll
  for (int rr=0; rr<4; rr++){
    int row = 4*w + rr;
    int sw = (row&7)<<3;
    float vals[16];
    float mx = -1e30f;
    #pragma unroll
    for (int j=0;j<16;j++){
      vals[j] = u.sc[row][(l + 64*j) ^ sw];
      mx = fmaxf(mx, vals[j]);
    }
    #pragma unroll
    for (int off=32; off>0; off>>=1) mx = fmaxf(mx, __shfl_xor(mx, off));
    float s = 0.f;
    #pragma unroll
    for (int j=0;j<16;j++){ vals[j] = __expf(vals[j]-mx); s += vals[j]; }
    #pragma unroll
    for (int off=32; off>0; off>>=1) s += __shfl_xor(s, off);
    float inv = 1.f / s;
    size_t gb = (((size_t)(b*8 + h))*1024 + (size_t)(r0 + row))*1024;
    #pragma unroll
    for (int j=0;j<16;j++){
      float a = vals[j]*inv;
      u.sc[row][(l + 64*j) ^ sw] = a;
      attn_out[gb + l + 64*j] = a;
    }
  }
  __syncthreads();

  // --- Phase E: PV — wave w owns head-dims 16w..16w+16 ---
  {
    f32x4 acc = {0.f,0.f,0.f,0.f};
    const short* vrow = vT + ((size_t)(bh*64 + 16*w + r))*1024;
    int sw = (r&7)<<3;
    for (int k0=0; k0<1024; k0+=32){
      int kb = (k0 + 8*g) ^ sw;
      const float* ap = &u.sc[r][kb];
      f32x4 f0 = *(const f32x4*)ap;
      f32x4 f1 = *(const f32x4*)(ap+4);
      bf16x8 af;
      af[0]=f2bf(f0[0]); af[1]=f2bf(f0[1]); af[2]=f2bf(f0[2]); af[3]=f2bf(f0[3]);
      af[4]=f2bf(f1[0]); af[5]=f2bf(f1[1]); af[6]=f2bf(f1[2]); af[7]=f2bf(f1[3]);
      bf16x8 bf = *(const bf16x8*)(vrow + k0 + 8*g);
      acc = __builtin_amdgcn_mfma_f32_16x16x32_bf16(af, bf, acc, 0,0,0);
    }
    size_t obase = ((size_t)(b*1024 + r0))*512 + (size_t)(h*64 + 16*w + r);
    #pragma unroll
    for (int rr=0; rr<4; rr++)
      cp[obase + (size_t)(4*g+rr)*512] = f2bf(acc[rr]);
  }
}

extern "C" void kernel_launch(void* const* d_in, const int* in_sizes, int n_in,
                              void* d_out, int out_size, void* d_ws, size_t ws_size,
                              hipStream_t stream){
  PP p;
  p.x1  = (const float*)d_in[0];
  p.x2  = (const float*)d_in[1];
  p.pe  = (const float*)d_in[2];
  p.mask= (const unsigned char*)d_in[3];
  p.Wq  = (const float*)d_in[4];  p.bq = (const float*)d_in[5];
  p.Wk  = (const float*)d_in[6];  p.bk = (const float*)d_in[7];
  p.Wv  = (const float*)d_in[8];  p.bv = (const float*)d_in[9];
  p.Wp  = (const float*)d_in[10];
  p.ub  = (const float*)d_in[11]; p.vb = (const float*)d_in[12];
  p.Wo1 = (const float*)d_in[13]; p.bo1= (const float*)d_in[14];
  p.Wo2 = (const float*)d_in[15]; p.bo2= (const float*)d_in[16];
  p.out = (float*)d_out;
  p.ws  = (char*)d_ws;

  hipLaunchKernelGGL(k_cvt,    dim3(1024,3), dim3(256), 0, stream, p);
  hipLaunchKernelGGL(k_cvtw,   dim3(64,6),   dim3(256), 0, stream, p);
  hipLaunchKernelGGL(k_gemm,   dim3(32,4,7), dim3(256), 0, stream, p, 0);
  hipLaunchKernelGGL(k_vtrans, dim3(16,32,2),dim3(256), 0, stream, p);
  hipLaunchKernelGGL(k_attn,   dim3(64,32,2),dim3(256), 0, stream, p);
  hipLaunchKernelGGL(k_gemm,   dim3(32,4,2), dim3(256), 0, stream, p, 7);
}